// Round 15
// baseline (310.167 us; speedup 1.0000x reference)
//
#include <hip/hip_runtime.h>
#include <hip/hip_bf16.h>

#define N_NODES 100000
#define N_EDGES 1000000
#define CH 128
#define KTOT 256
#define NCLS 3

#define NBKT 196                    // coarse buckets: dst>>9, 100000/512
#define EPB 16384                   // edges per partition block (4x r14: shrinks hist)
#define NB_A ((N_EDGES + EPB - 1) / EPB)          // 62
#define M_H (NBKT * NB_A)                          // 12152 -> 48.6 KB, fits LDS
#define CHK2 ((M_H + 1023) / 1024)                 // 12

#define NB_CVTX (N_NODES * CH / 4 / 256)           // 12500
#define NB_CVTW (KTOT * CH / 256)                  // 128
#define NB_A1 (NB_A + NB_CVTX + 2 * NB_CVTW)       // 12818

typedef __attribute__((ext_vector_type(8))) short v8s;   // 8 bf16 (A/B frag)
typedef __attribute__((ext_vector_type(4))) float v4f;   // 4 f32 (C/D frag)

__device__ __forceinline__ float bf2f(unsigned short u) {
    return __uint_as_float(((unsigned int)u) << 16);
}

__device__ __forceinline__ unsigned short f2bf(float f) {  // RNE
    unsigned int u = __float_as_uint(f);
    unsigned int r = (u + 0x7fffu + ((u >> 16) & 1u)) >> 16;
    return (unsigned short)r;
}

__device__ __forceinline__ int edge_at(const void* e, int is64, long long i) {
    if (is64) return (int)((const long long*)e)[i];
    return ((const int*)e)[i];
}

__device__ __forceinline__ float ldf(const void* p, int isbf, size_t i) {
    if (isbf) return bf2f(((const unsigned short*)p)[i]);
    return ((const float*)p)[i];
}

__device__ __forceinline__ void acc_u32(unsigned int u, float& a0, float& a1) {
    a0 += bf2f((unsigned short)(u & 0xffffu));
    a1 += bf2f((unsigned short)(u >> 16));
}

// --- K0: dtype sniffers only ---
__global__ void k_init(const void* __restrict__ e, const unsigned int* __restrict__ x,
                       int* __restrict__ eflag, int* __restrict__ dtf) {
    if (blockIdx.x == 0) {
        if (threadIdx.x < 64) {
            int v = ((const int*)e)[2 * threadIdx.x + 1];
            unsigned long long bl = __ballot(v != 0);
            if (threadIdx.x == 0) *eflag = (bl == 0ULL) ? 1 : 0;
        }
    } else {
        if (threadIdx.x < 64) {
            unsigned int u = x[threadIdx.x];
            int ex = (u >> 7) & 0xff;
            int sane = (ex == 0) || (ex >= 100 && ex <= 154);
            unsigned long long bl = __ballot(sane);
            if (threadIdx.x == 0) *dtf = (__popcll(bl) >= 48) ? 1 : 0;
        }
    }
}

// --- K1: coarse-bucket histogram (LDS atomics only) interleaved with cvt ---
__global__ void k_A1(const void* __restrict__ e, const int* __restrict__ eflag,
                     const int* __restrict__ dtf, int* __restrict__ hist,
                     const void* __restrict__ x, unsigned short* __restrict__ Abuf,
                     const void* __restrict__ wl1, const void* __restrict__ wr1,
                     unsigned short* __restrict__ WT1,
                     const void* __restrict__ wl2, const void* __restrict__ wr2,
                     unsigned short* __restrict__ WT2) {
    int b = blockIdx.x;
    int t = threadIdx.x;
    if (b < NB_A) {
        __shared__ int h[NBKT];
        if (t < NBKT) h[t] = 0;
        __syncthreads();
        int is64 = *eflag;
        for (int j = 0; j < EPB / 256; j++) {
            int i = b * EPB + j * 256 + t;
            if (i < N_EDGES) {
                int dst = edge_at(e, is64, (long long)N_EDGES + i);
                atomicAdd(&h[dst >> 9], 1);
            }
        }
        __syncthreads();
        if (t < NBKT) hist[t * NB_A + b] = h[t];
    } else {
        int ob = b - NB_A;
        if (ob < NB_CVTX) {
            int idx = ob * 256 + t;
            int node = idx >> 5;
            int ch = (idx & 31) * 4;
            int isbf = *dtf;
            unsigned short o[4];
            if (isbf) {
                ushort4 u = *(const ushort4*)((const unsigned short*)x +
                                              (size_t)node * CH + ch);
                o[0] = u.x; o[1] = u.y; o[2] = u.z; o[3] = u.w;
            } else {
                float4 v = *(const float4*)((const float*)x + (size_t)node * CH + ch);
                o[0] = f2bf(v.x); o[1] = f2bf(v.y); o[2] = f2bf(v.z); o[3] = f2bf(v.w);
            }
            *(ushort4*)(Abuf + (size_t)node * KTOT + CH + ch) =
                make_ushort4(o[0], o[1], o[2], o[3]);
        } else {
            int rel = ob - NB_CVTX;
            const void* wl = (rel < NB_CVTW) ? wl1 : wl2;
            const void* wr = (rel < NB_CVTW) ? wr1 : wr2;
            unsigned short* WT = (rel < NB_CVTW) ? WT1 : WT2;
            int i = (rel % NB_CVTW) * 256 + t;
            int k = i >> 7;
            int n = i & 127;
            int isbf = *dtf;
            float v = (k < CH) ? ldf(wl, isbf, (size_t)k * CH + n)
                               : ldf(wr, isbf, (size_t)(k - CH) * CH + n);
            WT[(size_t)n * KTOT + k] = f2bf(v);
        }
    }
}

// --- K2: exclusive scan over hist, entirely in LDS (r14's 52us spill-fest:
// CHK=47 register array spilled to scratch at VGPR=28 on a single CU) ---
__global__ __launch_bounds__(1024) void k_scanH(int* __restrict__ hist,
                                                int* __restrict__ bktbase) {
    __shared__ int s[M_H];
    __shared__ int ps[1024];
    int t = threadIdx.x;
    for (int i = t; i < M_H; i += 1024) s[i] = hist[i];  // coalesced load
    __syncthreads();
    int base0 = t * CHK2;
    int run = 0;
    #pragma unroll
    for (int j = 0; j < CHK2; j++) {  // in-place exclusive scan of own chunk
        int idx = base0 + j;
        if (idx < M_H) {
            int v = s[idx];
            s[idx] = run;
            run += v;
        }
    }
    ps[t] = run;
    __syncthreads();
    for (int off = 1; off < 1024; off <<= 1) {
        int v = (t >= off) ? ps[t - off] : 0;
        __syncthreads();
        ps[t] += v;
        __syncthreads();
    }
    int base = ps[t] - run;  // exclusive chunk base
    #pragma unroll
    for (int j = 0; j < CHK2; j++) {
        int idx = base0 + j;
        if (idx < M_H) s[idx] += base;
    }
    __syncthreads();
    for (int i = t; i < M_H; i += 1024) hist[i] = s[i];  // coalesced store
    __syncthreads();
    if (t < NBKT) bktbase[t] = s[t * NB_A];
    if (t == 0) bktbase[NBKT] = N_EDGES;
}

// --- K3: partition scatter via LDS cursors; pack (src<<9)|(dst&511) ---
__global__ void k_A3(const void* __restrict__ e, const int* __restrict__ eflag,
                     const int* __restrict__ hist, unsigned int* __restrict__ part) {
    __shared__ int cur[NBKT];
    int b = blockIdx.x;
    int t = threadIdx.x;
    if (t < NBKT) cur[t] = hist[t * NB_A + b];
    __syncthreads();
    int is64 = *eflag;
    for (int j = 0; j < EPB / 256; j++) {
        int i = b * EPB + j * 256 + t;
        if (i < N_EDGES) {
            int src = edge_at(e, is64, i);
            int dst = edge_at(e, is64, (long long)N_EDGES + i);
            int pos = atomicAdd(&cur[dst >> 9], 1);  // LDS atomic
            part[pos] = ((unsigned int)src << 9) | (unsigned int)(dst & 511);
        }
    }
}

// --- K4: per-bucket finalize: degree count + scan -> row_start + csr_src ---
__global__ __launch_bounds__(1024) void k_B(const int* __restrict__ bktbase,
                                            const unsigned int* __restrict__ part,
                                            int* __restrict__ row_start,
                                            int* __restrict__ csr_src) {
    __shared__ int dcnt[512], sa[512], curs[512];
    int b = blockIdx.x;
    int t = threadIdx.x;
    int e0 = bktbase[b], e1 = bktbase[b + 1];
    if (t < 512) dcnt[t] = 0;
    __syncthreads();
    for (int i = e0 + t; i < e1; i += 1024)
        atomicAdd(&dcnt[part[i] & 511], 1);
    __syncthreads();
    if (t < 512) sa[t] = dcnt[t];
    __syncthreads();
    for (int off = 1; off < 512; off <<= 1) {
        int v = 0;
        if (t < 512 && t >= off) v = sa[t - off];
        __syncthreads();
        if (t < 512) sa[t] += v;
        __syncthreads();
    }
    if (t < 512) {
        int excl = sa[t] - dcnt[t];
        curs[t] = e0 + excl;
        int node = b * 512 + t;
        if (node < N_NODES) row_start[node] = e0 + excl;
    }
    if (b == 0 && t == 0) row_start[N_NODES] = N_EDGES;
    __syncthreads();
    for (int i = e0 + t; i < e1; i += 1024) {
        unsigned int p = part[i];
        int pos = atomicAdd(&curs[p & 511], 1);  // LDS atomic
        csr_src[pos] = (int)(p >> 9);
    }
}

// --- gather-mean: 4 nodes/wave, 16 lanes/node, 8 edges in flight ---
__global__ __launch_bounds__(256) void k_agg(
    const int* __restrict__ row_start, const int* __restrict__ csr_src,
    const unsigned short* __restrict__ gsrc, unsigned short* __restrict__ gdst) {
    long long gt = (long long)blockIdx.x * blockDim.x + threadIdx.x;
    int node = (int)(gt >> 4);
    int lane = (int)(gt & 15);
    if (node >= N_NODES) return;
    int beg = row_start[node];
    int end = row_start[node + 1];
    float a[8];
#pragma unroll
    for (int j = 0; j < 8; j++) a[j] = 0.f;
    int e = beg;
    while (e + 8 <= end) {
        int s[8];
#pragma unroll
        for (int j = 0; j < 8; j++) s[j] = csr_src[e + j];
        uint4 u[8];
#pragma unroll
        for (int j = 0; j < 8; j++)
            u[j] = *(const uint4*)(gsrc + (size_t)s[j] * KTOT + CH + lane * 8);
#pragma unroll
        for (int j = 0; j < 8; j++) {
            acc_u32(u[j].x, a[0], a[1]); acc_u32(u[j].y, a[2], a[3]);
            acc_u32(u[j].z, a[4], a[5]); acc_u32(u[j].w, a[6], a[7]);
        }
        e += 8;
    }
    while (e + 2 <= end) {
        int s0 = csr_src[e], s1 = csr_src[e + 1];
        uint4 u0 = *(const uint4*)(gsrc + (size_t)s0 * KTOT + CH + lane * 8);
        uint4 u1 = *(const uint4*)(gsrc + (size_t)s1 * KTOT + CH + lane * 8);
        acc_u32(u0.x, a[0], a[1]); acc_u32(u0.y, a[2], a[3]);
        acc_u32(u0.z, a[4], a[5]); acc_u32(u0.w, a[6], a[7]);
        acc_u32(u1.x, a[0], a[1]); acc_u32(u1.y, a[2], a[3]);
        acc_u32(u1.z, a[4], a[5]); acc_u32(u1.w, a[6], a[7]);
        e += 2;
    }
    if (e < end) {
        int s0 = csr_src[e];
        uint4 u0 = *(const uint4*)(gsrc + (size_t)s0 * KTOT + CH + lane * 8);
        acc_u32(u0.x, a[0], a[1]); acc_u32(u0.y, a[2], a[3]);
        acc_u32(u0.z, a[4], a[5]); acc_u32(u0.w, a[6], a[7]);
    }
    float rinv = 1.0f / (float)max(end - beg, 1);
    unsigned int p0 = (unsigned int)f2bf(a[0] * rinv) | ((unsigned int)f2bf(a[1] * rinv) << 16);
    unsigned int p1 = (unsigned int)f2bf(a[2] * rinv) | ((unsigned int)f2bf(a[3] * rinv) << 16);
    unsigned int p2 = (unsigned int)f2bf(a[4] * rinv) | ((unsigned int)f2bf(a[5] * rinv) << 16);
    unsigned int p3 = (unsigned int)f2bf(a[6] * rinv) | ((unsigned int)f2bf(a[7] * rinv) << 16);
    *(uint4*)(gdst + (size_t)node * KTOT + lane * 8) = make_uint4(p0, p1, p2, p3);
}

// --- MFMA GEMM, double-buffered; optional fused classifier epilogue ---
#define LDK 40
#define CLS_LD 130
__global__ __launch_bounds__(256) void k_gemm_mfma(
    const unsigned short* __restrict__ Abuf, const unsigned short* __restrict__ WT,
    const void* __restrict__ bias, const int* __restrict__ dtf,
    unsigned short* __restrict__ out, int out_stride, int out_off,
    const void* __restrict__ wcls, const void* __restrict__ bcls,
    float* __restrict__ cls_out) {
    __shared__ unsigned short smem[4 * 128 * LDK];
    __shared__ float wcls_s[CH * NCLS];
    unsigned short* As = smem;
    unsigned short* Bs = smem + 2 * 128 * LDK;
    const int t = threadIdx.x;
    const int w = t >> 6, l = t & 63;
    const int wx = w & 1, wy = w >> 1;
    const int quad = l >> 4, lrow = l & 15;
    const int row0 = blockIdx.x * 128;
    const int srow = t >> 1, shalf = t & 1;
    const int isbf = *dtf;

    if (cls_out) {
        for (int i = t; i < CH * NCLS; i += 256) wcls_s[i] = ldf(wcls, isbf, i);
    }

    int ar = row0 + srow;
    if (ar >= N_NODES) ar = N_NODES - 1;
    const unsigned short* abase = Abuf + (size_t)ar * KTOT + shalf * 16;
    const unsigned short* bbase = WT + (size_t)srow * KTOT + shalf * 16;

    v4f acc[4][4];
#pragma unroll
    for (int i = 0; i < 4; i++)
#pragma unroll
        for (int j = 0; j < 4; j++) acc[i][j] = (v4f){0.f, 0.f, 0.f, 0.f};

    {
        uint4 a0 = *(const uint4*)abase, a1 = *(const uint4*)(abase + 8);
        uint4 b0 = *(const uint4*)bbase, b1 = *(const uint4*)(bbase + 8);
        *(uint4*)&As[srow * LDK + shalf * 16] = a0;
        *(uint4*)&As[srow * LDK + shalf * 16 + 8] = a1;
        *(uint4*)&Bs[srow * LDK + shalf * 16] = b0;
        *(uint4*)&Bs[srow * LDK + shalf * 16 + 8] = b1;
    }
#pragma unroll
    for (int k = 0; k < KTOT / 32; k++) {
        uint4 na0, na1, nb0, nb1;
        if (k < KTOT / 32 - 1) {
            na0 = *(const uint4*)(abase + (k + 1) * 32);
            na1 = *(const uint4*)(abase + (k + 1) * 32 + 8);
            nb0 = *(const uint4*)(bbase + (k + 1) * 32);
            nb1 = *(const uint4*)(bbase + (k + 1) * 32 + 8);
        }
        __syncthreads();
        const int cur = (k & 1) * 128 * LDK, nxt = ((k + 1) & 1) * 128 * LDK;
        v8s af[4], bfr[4];
#pragma unroll
        for (int mi = 0; mi < 4; mi++)
            af[mi] = *(const v8s*)&As[cur + (wy * 64 + mi * 16 + lrow) * LDK + quad * 8];
#pragma unroll
        for (int ni = 0; ni < 4; ni++)
            bfr[ni] = *(const v8s*)&Bs[cur + (wx * 64 + ni * 16 + lrow) * LDK + quad * 8];
#pragma unroll
        for (int mi = 0; mi < 4; mi++)
#pragma unroll
            for (int ni = 0; ni < 4; ni++)
                acc[mi][ni] = __builtin_amdgcn_mfma_f32_16x16x32_bf16(
                    af[mi], bfr[ni], acc[mi][ni], 0, 0, 0);
        if (k < KTOT / 32 - 1) {
            *(uint4*)&As[nxt + srow * LDK + shalf * 16] = na0;
            *(uint4*)&As[nxt + srow * LDK + shalf * 16 + 8] = na1;
            *(uint4*)&Bs[nxt + srow * LDK + shalf * 16] = nb0;
            *(uint4*)&Bs[nxt + srow * LDK + shalf * 16 + 8] = nb1;
        }
    }
    float bj[4];
#pragma unroll
    for (int ni = 0; ni < 4; ni++) bj[ni] = ldf(bias, isbf, wx * 64 + ni * 16 + lrow);

    if (!cls_out) {
#pragma unroll
        for (int mi = 0; mi < 4; mi++) {
#pragma unroll
            for (int r = 0; r < 4; r++) {
                int grow = row0 + wy * 64 + mi * 16 + quad * 4 + r;
                if (grow < N_NODES) {
#pragma unroll
                    for (int ni = 0; ni < 4; ni++) {
                        int col = wx * 64 + ni * 16 + lrow;
                        float v = fmaxf(acc[mi][ni][r] + bj[ni], 0.0f);
                        out[(size_t)grow * out_stride + out_off + col] = f2bf(v);
                    }
                }
            }
        }
    } else {
        __syncthreads();
#pragma unroll
        for (int mi = 0; mi < 4; mi++) {
#pragma unroll
            for (int r = 0; r < 4; r++) {
                int row = wy * 64 + mi * 16 + quad * 4 + r;
#pragma unroll
                for (int ni = 0; ni < 4; ni++) {
                    int col = wx * 64 + ni * 16 + lrow;
                    float v = fmaxf(acc[mi][ni][r] + bj[ni], 0.0f);
                    smem[row * CLS_LD + col] = f2bf(v);
                }
            }
        }
        __syncthreads();
        if (t < 128) {
            int grow = row0 + t;
            if (grow < N_NODES) {
                float a0 = 0.f, a1 = 0.f, a2 = 0.f;
                for (int k = 0; k < CH; k++) {
                    float h = bf2f(smem[t * CLS_LD + k]);
                    a0 += h * wcls_s[k * NCLS + 0];
                    a1 += h * wcls_s[k * NCLS + 1];
                    a2 += h * wcls_s[k * NCLS + 2];
                }
                cls_out[(size_t)grow * NCLS + 0] = a0 + ldf(bcls, isbf, 0);
                cls_out[(size_t)grow * NCLS + 1] = a1 + ldf(bcls, isbf, 1);
                cls_out[(size_t)grow * NCLS + 2] = a2 + ldf(bcls, isbf, 2);
            }
        }
    }
}

extern "C" void kernel_launch(void* const* d_in, const int* in_sizes, int n_in,
                              void* d_out, int out_size, void* d_ws, size_t ws_size,
                              hipStream_t stream) {
    const void* x = d_in[0];
    const void* eidx = d_in[1];
    const void* w_l1 = d_in[2];
    const void* b_l1 = d_in[3];
    const void* w_r1 = d_in[4];
    const void* w_l2 = d_in[5];
    const void* b_l2 = d_in[6];
    const void* w_r2 = d_in[7];
    const void* w_cls = d_in[8];
    const void* b_cls = d_in[9];

    char* w = (char*)d_ws;
    int* eflag = (int*)w;
    int* dtf = (int*)(w + 64);
    int* hist = (int*)(w + 4096);                            // 48,608 B
    int* bktbase = (int*)(w + 196608);                       // 788 B
    int* row_start = (int*)(w + 262144);                     // 400,004 B
    unsigned int* part = (unsigned int*)(w + 720896);        // 4 MB
    int* csr_src = (int*)(w + 4915200);                      // 4 MB
    unsigned short* WT1 = (unsigned short*)(w + 8978432);    // 64 KB
    unsigned short* WT2 = (unsigned short*)(w + 9043968);    // 64 KB
    unsigned short* A1 = (unsigned short*)(w + 11534336);    // 51.2 MB
    unsigned short* A2 = (unsigned short*)(w + 62914560);    // 51.2 MB (ends 114.1 MB, proven)

    hipLaunchKernelGGL(k_init, dim3(2), dim3(256), 0, stream,
                       eidx, (const unsigned int*)x, eflag, dtf);
    hipLaunchKernelGGL(k_A1, dim3(NB_A1), dim3(256), 0, stream,
                       eidx, eflag, dtf, hist, x, A1,
                       w_l1, w_r1, WT1, w_l2, w_r2, WT2);
    hipLaunchKernelGGL(k_scanH, dim3(1), dim3(1024), 0, stream, hist, bktbase);
    hipLaunchKernelGGL(k_A3, dim3(NB_A), dim3(256), 0, stream,
                       eidx, eflag, hist, part);
    hipLaunchKernelGGL(k_B, dim3(NBKT), dim3(1024), 0, stream,
                       bktbase, part, row_start, csr_src);
    // layer 1
    hipLaunchKernelGGL(k_agg, dim3(N_NODES * 16 / 256), dim3(256), 0, stream,
                       row_start, csr_src, A1, A1);
    hipLaunchKernelGGL(k_gemm_mfma, dim3((N_NODES + 127) / 128), dim3(256), 0, stream,
                       A1, WT1, b_l1, dtf, A2, KTOT, CH,
                       (const void*)nullptr, (const void*)nullptr, (float*)nullptr);
    // layer 2 + fused classifier
    hipLaunchKernelGGL(k_agg, dim3(N_NODES * 16 / 256), dim3(256), 0, stream,
                       row_start, csr_src, A2, A2);
    hipLaunchKernelGGL(k_gemm_mfma, dim3((N_NODES + 127) / 128), dim3(256), 0, stream,
                       A2, WT2, b_l2, dtf, (unsigned short*)nullptr, 0, 0,
                       w_cls, b_cls, (float*)d_out);
}

// Round 16
// 266.136 us; speedup vs baseline: 1.1654x; 1.1654x over previous
//
#include <hip/hip_runtime.h>
#include <hip/hip_bf16.h>

#define N_NODES 100000
#define N_EDGES 1000000
#define CH 128
#define KTOT 256
#define NCLS 3

#define NBKT 196                    // coarse buckets: dst>>9
#define EPB 4096                    // edges per partition block (parallelism!)
#define NB_A ((N_EDGES + EPB - 1) / EPB)          // 245
#define M_H (NBKT * NB_A)                          // 48020
#define NB_SCAN ((M_H + 1023) / 1024)              // 47 co-resident blocks

#define NB_CVTX (N_NODES * CH / 4 / 256)           // 12500
#define NB_CVTW (KTOT * CH / 256)                  // 128
#define NB_A1 (NB_A + NB_CVTX + 2 * NB_CVTW)       // 13001

typedef __attribute__((ext_vector_type(8))) short v8s;   // 8 bf16 (A/B frag)
typedef __attribute__((ext_vector_type(4))) float v4f;   // 4 f32 (C/D frag)

__device__ __forceinline__ float bf2f(unsigned short u) {
    return __uint_as_float(((unsigned int)u) << 16);
}

__device__ __forceinline__ unsigned short f2bf(float f) {  // RNE
    unsigned int u = __float_as_uint(f);
    unsigned int r = (u + 0x7fffu + ((u >> 16) & 1u)) >> 16;
    return (unsigned short)r;
}

__device__ __forceinline__ int edge_at(const void* e, int is64, long long i) {
    if (is64) return (int)((const long long*)e)[i];
    return ((const int*)e)[i];
}

__device__ __forceinline__ float ldf(const void* p, int isbf, size_t i) {
    if (isbf) return bf2f(((const unsigned short*)p)[i]);
    return ((const float*)p)[i];
}

__device__ __forceinline__ void acc_u32(unsigned int u, float& a0, float& a1) {
    a0 += bf2f((unsigned short)(u & 0xffffu));
    a1 += bf2f((unsigned short)(u >> 16));
}

// --- K0: dtype sniffers + done flag ---
__global__ void k_init(const void* __restrict__ e, const unsigned int* __restrict__ x,
                       int* __restrict__ eflag, int* __restrict__ dtf,
                       int* __restrict__ done) {
    if (blockIdx.x == 0) {
        if (threadIdx.x < 64) {
            int v = ((const int*)e)[2 * threadIdx.x + 1];
            unsigned long long bl = __ballot(v != 0);
            if (threadIdx.x == 0) *eflag = (bl == 0ULL) ? 1 : 0;
        } else if (threadIdx.x == 64) {
            *done = 0;
        }
    } else {
        if (threadIdx.x < 64) {
            unsigned int u = x[threadIdx.x];
            int ex = (u >> 7) & 0xff;
            int sane = (ex == 0) || (ex >= 100 && ex <= 154);
            unsigned long long bl = __ballot(sane);
            if (threadIdx.x == 0) *dtf = (__popcll(bl) >= 48) ? 1 : 0;
        }
    }
}

// --- K1: coarse-bucket histogram (LDS atomics only) interleaved with cvt ---
__global__ void k_A1(const void* __restrict__ e, const int* __restrict__ eflag,
                     const int* __restrict__ dtf, int* __restrict__ hist,
                     const void* __restrict__ x, unsigned short* __restrict__ Abuf,
                     const void* __restrict__ wl1, const void* __restrict__ wr1,
                     unsigned short* __restrict__ WT1,
                     const void* __restrict__ wl2, const void* __restrict__ wr2,
                     unsigned short* __restrict__ WT2) {
    int b = blockIdx.x;
    int t = threadIdx.x;
    if (b < NB_A) {
        __shared__ int h[NBKT];
        if (t < NBKT) h[t] = 0;
        __syncthreads();
        int is64 = *eflag;
#pragma unroll
        for (int j = 0; j < EPB / 256; j++) {
            int i = b * EPB + j * 256 + t;
            if (i < N_EDGES) {
                int dst = edge_at(e, is64, (long long)N_EDGES + i);
                atomicAdd(&h[dst >> 9], 1);
            }
        }
        __syncthreads();
        if (t < NBKT) hist[t * NB_A + b] = h[t];
    } else {
        int ob = b - NB_A;
        if (ob < NB_CVTX) {
            int idx = ob * 256 + t;
            int node = idx >> 5;
            int ch = (idx & 31) * 4;
            int isbf = *dtf;
            unsigned short o[4];
            if (isbf) {
                ushort4 u = *(const ushort4*)((const unsigned short*)x +
                                              (size_t)node * CH + ch);
                o[0] = u.x; o[1] = u.y; o[2] = u.z; o[3] = u.w;
            } else {
                float4 v = *(const float4*)((const float*)x + (size_t)node * CH + ch);
                o[0] = f2bf(v.x); o[1] = f2bf(v.y); o[2] = f2bf(v.z); o[3] = f2bf(v.w);
            }
            *(ushort4*)(Abuf + (size_t)node * KTOT + CH + ch) =
                make_ushort4(o[0], o[1], o[2], o[3]);
        } else {
            int rel = ob - NB_CVTX;
            const void* wl = (rel < NB_CVTW) ? wl1 : wl2;
            const void* wr = (rel < NB_CVTW) ? wr1 : wr2;
            unsigned short* WT = (rel < NB_CVTW) ? WT1 : WT2;
            int i = (rel % NB_CVTW) * 256 + t;
            int k = i >> 7;
            int n = i & 127;
            int isbf = *dtf;
            float v = (k < CH) ? ldf(wl, isbf, (size_t)k * CH + n)
                               : ldf(wr, isbf, (size_t)(k - CH) * CH + n);
            WT[(size_t)n * KTOT + k] = f2bf(v);
        }
    }
}

// --- K2: multi-block exclusive scan, producer-only spin barrier (r10 pattern:
// safe because EVERY spinning block is also a producer; r11's failure mode was
// 390 non-producer spinners) ---
__global__ __launch_bounds__(1024) void k_scanH(int* __restrict__ hist,
                                                int* __restrict__ bsum,
                                                int* __restrict__ done) {
    __shared__ int s[1024];
    __shared__ int pre_sh;
    int t = threadIdx.x, b = blockIdx.x;
    int idx = b * 1024 + t;
    int v = (idx < M_H) ? hist[idx] : 0;
    s[t] = v;
    __syncthreads();
    for (int off = 1; off < 1024; off <<= 1) {
        int u = (t >= off) ? s[t - off] : 0;
        __syncthreads();
        s[t] += u;
        __syncthreads();
    }
    if (t == 1023) {
        bsum[b] = s[t];
        __threadfence();
        atomicAdd(done, 1);
    }
    if (t == 0) {
        while (__hip_atomic_load(done, __ATOMIC_ACQUIRE,
                                 __HIP_MEMORY_SCOPE_AGENT) < NB_SCAN) {
        }
        __threadfence();
        int run = 0;
        for (int r = 0; r < b; r++) run += bsum[r];
        pre_sh = run;
    }
    __syncthreads();
    if (idx < M_H) hist[idx] = s[t] - v + pre_sh;  // exclusive
}

// --- K3: partition scatter via LDS cursors; pack (src<<9)|(dst&511) ---
__global__ void k_A3(const void* __restrict__ e, const int* __restrict__ eflag,
                     const int* __restrict__ hist, unsigned int* __restrict__ part) {
    __shared__ int cur[NBKT];
    int b = blockIdx.x;
    int t = threadIdx.x;
    if (t < NBKT) cur[t] = hist[t * NB_A + b];
    __syncthreads();
    int is64 = *eflag;
#pragma unroll
    for (int j = 0; j < EPB / 256; j++) {
        int i = b * EPB + j * 256 + t;
        if (i < N_EDGES) {
            int src = edge_at(e, is64, i);
            int dst = edge_at(e, is64, (long long)N_EDGES + i);
            int pos = atomicAdd(&cur[dst >> 9], 1);  // LDS atomic
            part[pos] = ((unsigned int)src << 9) | (unsigned int)(dst & 511);
        }
    }
}

// --- K4: per-bucket finalize: degree count + scan -> row_start + csr_src ---
__global__ __launch_bounds__(1024) void k_B(const int* __restrict__ hist,
                                            const unsigned int* __restrict__ part,
                                            int* __restrict__ row_start,
                                            int* __restrict__ csr_src) {
    __shared__ int dcnt[512], sa[512], curs[512];
    int b = blockIdx.x;
    int t = threadIdx.x;
    int e0 = hist[b * NB_A];
    int e1 = (b + 1 < NBKT) ? hist[(b + 1) * NB_A] : N_EDGES;
    if (t < 512) dcnt[t] = 0;
    __syncthreads();
    for (int i = e0 + t; i < e1; i += 1024)
        atomicAdd(&dcnt[part[i] & 511], 1);
    __syncthreads();
    if (t < 512) sa[t] = dcnt[t];
    __syncthreads();
    for (int off = 1; off < 512; off <<= 1) {
        int v = 0;
        if (t < 512 && t >= off) v = sa[t - off];
        __syncthreads();
        if (t < 512) sa[t] += v;
        __syncthreads();
    }
    if (t < 512) {
        int excl = sa[t] - dcnt[t];
        curs[t] = e0 + excl;
        int node = b * 512 + t;
        if (node < N_NODES) row_start[node] = e0 + excl;
    }
    if (b == 0 && t == 0) row_start[N_NODES] = N_EDGES;
    __syncthreads();
    for (int i = e0 + t; i < e1; i += 1024) {
        unsigned int p = part[i];
        int pos = atomicAdd(&curs[p & 511], 1);  // LDS atomic
        csr_src[pos] = (int)(p >> 9);
    }
}

// --- gather-mean: 4 nodes/wave, 16 lanes/node, 8 edges in flight ---
__global__ __launch_bounds__(256) void k_agg(
    const int* __restrict__ row_start, const int* __restrict__ csr_src,
    const unsigned short* __restrict__ gsrc, unsigned short* __restrict__ gdst) {
    long long gt = (long long)blockIdx.x * blockDim.x + threadIdx.x;
    int node = (int)(gt >> 4);
    int lane = (int)(gt & 15);
    if (node >= N_NODES) return;
    int beg = row_start[node];
    int end = row_start[node + 1];
    float a[8];
#pragma unroll
    for (int j = 0; j < 8; j++) a[j] = 0.f;
    int e = beg;
    while (e + 8 <= end) {
        int s[8];
#pragma unroll
        for (int j = 0; j < 8; j++) s[j] = csr_src[e + j];
        uint4 u[8];
#pragma unroll
        for (int j = 0; j < 8; j++)
            u[j] = *(const uint4*)(gsrc + (size_t)s[j] * KTOT + CH + lane * 8);
#pragma unroll
        for (int j = 0; j < 8; j++) {
            acc_u32(u[j].x, a[0], a[1]); acc_u32(u[j].y, a[2], a[3]);
            acc_u32(u[j].z, a[4], a[5]); acc_u32(u[j].w, a[6], a[7]);
        }
        e += 8;
    }
    while (e + 2 <= end) {
        int s0 = csr_src[e], s1 = csr_src[e + 1];
        uint4 u0 = *(const uint4*)(gsrc + (size_t)s0 * KTOT + CH + lane * 8);
        uint4 u1 = *(const uint4*)(gsrc + (size_t)s1 * KTOT + CH + lane * 8);
        acc_u32(u0.x, a[0], a[1]); acc_u32(u0.y, a[2], a[3]);
        acc_u32(u0.z, a[4], a[5]); acc_u32(u0.w, a[6], a[7]);
        acc_u32(u1.x, a[0], a[1]); acc_u32(u1.y, a[2], a[3]);
        acc_u32(u1.z, a[4], a[5]); acc_u32(u1.w, a[6], a[7]);
        e += 2;
    }
    if (e < end) {
        int s0 = csr_src[e];
        uint4 u0 = *(const uint4*)(gsrc + (size_t)s0 * KTOT + CH + lane * 8);
        acc_u32(u0.x, a[0], a[1]); acc_u32(u0.y, a[2], a[3]);
        acc_u32(u0.z, a[4], a[5]); acc_u32(u0.w, a[6], a[7]);
    }
    float rinv = 1.0f / (float)max(end - beg, 1);
    unsigned int p0 = (unsigned int)f2bf(a[0] * rinv) | ((unsigned int)f2bf(a[1] * rinv) << 16);
    unsigned int p1 = (unsigned int)f2bf(a[2] * rinv) | ((unsigned int)f2bf(a[3] * rinv) << 16);
    unsigned int p2 = (unsigned int)f2bf(a[4] * rinv) | ((unsigned int)f2bf(a[5] * rinv) << 16);
    unsigned int p3 = (unsigned int)f2bf(a[6] * rinv) | ((unsigned int)f2bf(a[7] * rinv) << 16);
    *(uint4*)(gdst + (size_t)node * KTOT + lane * 8) = make_uint4(p0, p1, p2, p3);
}

// --- MFMA GEMM, double-buffered; optional fused classifier epilogue ---
#define LDK 40
#define CLS_LD 130
__global__ __launch_bounds__(256) void k_gemm_mfma(
    const unsigned short* __restrict__ Abuf, const unsigned short* __restrict__ WT,
    const void* __restrict__ bias, const int* __restrict__ dtf,
    unsigned short* __restrict__ out, int out_stride, int out_off,
    const void* __restrict__ wcls, const void* __restrict__ bcls,
    float* __restrict__ cls_out) {
    __shared__ unsigned short smem[4 * 128 * LDK];
    __shared__ float wcls_s[CH * NCLS];
    unsigned short* As = smem;
    unsigned short* Bs = smem + 2 * 128 * LDK;
    const int t = threadIdx.x;
    const int w = t >> 6, l = t & 63;
    const int wx = w & 1, wy = w >> 1;
    const int quad = l >> 4, lrow = l & 15;
    const int row0 = blockIdx.x * 128;
    const int srow = t >> 1, shalf = t & 1;
    const int isbf = *dtf;

    if (cls_out) {
        for (int i = t; i < CH * NCLS; i += 256) wcls_s[i] = ldf(wcls, isbf, i);
    }

    int ar = row0 + srow;
    if (ar >= N_NODES) ar = N_NODES - 1;
    const unsigned short* abase = Abuf + (size_t)ar * KTOT + shalf * 16;
    const unsigned short* bbase = WT + (size_t)srow * KTOT + shalf * 16;

    v4f acc[4][4];
#pragma unroll
    for (int i = 0; i < 4; i++)
#pragma unroll
        for (int j = 0; j < 4; j++) acc[i][j] = (v4f){0.f, 0.f, 0.f, 0.f};

    {
        uint4 a0 = *(const uint4*)abase, a1 = *(const uint4*)(abase + 8);
        uint4 b0 = *(const uint4*)bbase, b1 = *(const uint4*)(bbase + 8);
        *(uint4*)&As[srow * LDK + shalf * 16] = a0;
        *(uint4*)&As[srow * LDK + shalf * 16 + 8] = a1;
        *(uint4*)&Bs[srow * LDK + shalf * 16] = b0;
        *(uint4*)&Bs[srow * LDK + shalf * 16 + 8] = b1;
    }
#pragma unroll
    for (int k = 0; k < KTOT / 32; k++) {
        uint4 na0, na1, nb0, nb1;
        if (k < KTOT / 32 - 1) {
            na0 = *(const uint4*)(abase + (k + 1) * 32);
            na1 = *(const uint4*)(abase + (k + 1) * 32 + 8);
            nb0 = *(const uint4*)(bbase + (k + 1) * 32);
            nb1 = *(const uint4*)(bbase + (k + 1) * 32 + 8);
        }
        __syncthreads();
        const int cur = (k & 1) * 128 * LDK, nxt = ((k + 1) & 1) * 128 * LDK;
        v8s af[4], bfr[4];
#pragma unroll
        for (int mi = 0; mi < 4; mi++)
            af[mi] = *(const v8s*)&As[cur + (wy * 64 + mi * 16 + lrow) * LDK + quad * 8];
#pragma unroll
        for (int ni = 0; ni < 4; ni++)
            bfr[ni] = *(const v8s*)&Bs[cur + (wx * 64 + ni * 16 + lrow) * LDK + quad * 8];
#pragma unroll
        for (int mi = 0; mi < 4; mi++)
#pragma unroll
            for (int ni = 0; ni < 4; ni++)
                acc[mi][ni] = __builtin_amdgcn_mfma_f32_16x16x32_bf16(
                    af[mi], bfr[ni], acc[mi][ni], 0, 0, 0);
        if (k < KTOT / 32 - 1) {
            *(uint4*)&As[nxt + srow * LDK + shalf * 16] = na0;
            *(uint4*)&As[nxt + srow * LDK + shalf * 16 + 8] = na1;
            *(uint4*)&Bs[nxt + srow * LDK + shalf * 16] = nb0;
            *(uint4*)&Bs[nxt + srow * LDK + shalf * 16 + 8] = nb1;
        }
    }
    float bj[4];
#pragma unroll
    for (int ni = 0; ni < 4; ni++) bj[ni] = ldf(bias, isbf, wx * 64 + ni * 16 + lrow);

    if (!cls_out) {
#pragma unroll
        for (int mi = 0; mi < 4; mi++) {
#pragma unroll
            for (int r = 0; r < 4; r++) {
                int grow = row0 + wy * 64 + mi * 16 + quad * 4 + r;
                if (grow < N_NODES) {
#pragma unroll
                    for (int ni = 0; ni < 4; ni++) {
                        int col = wx * 64 + ni * 16 + lrow;
                        float v = fmaxf(acc[mi][ni][r] + bj[ni], 0.0f);
                        out[(size_t)grow * out_stride + out_off + col] = f2bf(v);
                    }
                }
            }
        }
    } else {
        __syncthreads();
#pragma unroll
        for (int mi = 0; mi < 4; mi++) {
#pragma unroll
            for (int r = 0; r < 4; r++) {
                int row = wy * 64 + mi * 16 + quad * 4 + r;
#pragma unroll
                for (int ni = 0; ni < 4; ni++) {
                    int col = wx * 64 + ni * 16 + lrow;
                    float v = fmaxf(acc[mi][ni][r] + bj[ni], 0.0f);
                    smem[row * CLS_LD + col] = f2bf(v);
                }
            }
        }
        __syncthreads();
        if (t < 128) {
            int grow = row0 + t;
            if (grow < N_NODES) {
                float a0 = 0.f, a1 = 0.f, a2 = 0.f;
                for (int k = 0; k < CH; k++) {
                    float h = bf2f(smem[t * CLS_LD + k]);
                    a0 += h * wcls_s[k * NCLS + 0];
                    a1 += h * wcls_s[k * NCLS + 1];
                    a2 += h * wcls_s[k * NCLS + 2];
                }
                cls_out[(size_t)grow * NCLS + 0] = a0 + ldf(bcls, isbf, 0);
                cls_out[(size_t)grow * NCLS + 1] = a1 + ldf(bcls, isbf, 1);
                cls_out[(size_t)grow * NCLS + 2] = a2 + ldf(bcls, isbf, 2);
            }
        }
    }
}

extern "C" void kernel_launch(void* const* d_in, const int* in_sizes, int n_in,
                              void* d_out, int out_size, void* d_ws, size_t ws_size,
                              hipStream_t stream) {
    const void* x = d_in[0];
    const void* eidx = d_in[1];
    const void* w_l1 = d_in[2];
    const void* b_l1 = d_in[3];
    const void* w_r1 = d_in[4];
    const void* w_l2 = d_in[5];
    const void* b_l2 = d_in[6];
    const void* w_r2 = d_in[7];
    const void* w_cls = d_in[8];
    const void* b_cls = d_in[9];

    char* w = (char*)d_ws;
    int* eflag = (int*)w;
    int* dtf = (int*)(w + 64);
    int* done = (int*)(w + 128);
    int* hist = (int*)(w + 4096);                            // 192,080 B
    int* bsum = (int*)(w + 196608);                          // 188 B
    int* row_start = (int*)(w + 262144);                     // 400,004 B
    unsigned int* part = (unsigned int*)(w + 720896);        // 4 MB
    int* csr_src = (int*)(w + 4915200);                      // 4 MB
    unsigned short* WT1 = (unsigned short*)(w + 8978432);    // 64 KB
    unsigned short* WT2 = (unsigned short*)(w + 9043968);    // 64 KB
    unsigned short* A1 = (unsigned short*)(w + 11534336);    // 51.2 MB
    unsigned short* A2 = (unsigned short*)(w + 62914560);    // 51.2 MB (ends 114.1 MB, proven)

    hipLaunchKernelGGL(k_init, dim3(2), dim3(256), 0, stream,
                       eidx, (const unsigned int*)x, eflag, dtf, done);
    hipLaunchKernelGGL(k_A1, dim3(NB_A1), dim3(256), 0, stream,
                       eidx, eflag, dtf, hist, x, A1,
                       w_l1, w_r1, WT1, w_l2, w_r2, WT2);
    hipLaunchKernelGGL(k_scanH, dim3(NB_SCAN), dim3(1024), 0, stream,
                       hist, bsum, done);
    hipLaunchKernelGGL(k_A3, dim3(NB_A), dim3(256), 0, stream,
                       eidx, eflag, hist, part);
    hipLaunchKernelGGL(k_B, dim3(NBKT), dim3(1024), 0, stream,
                       hist, part, row_start, csr_src);
    // layer 1
    hipLaunchKernelGGL(k_agg, dim3(N_NODES * 16 / 256), dim3(256), 0, stream,
                       row_start, csr_src, A1, A1);
    hipLaunchKernelGGL(k_gemm_mfma, dim3((N_NODES + 127) / 128), dim3(256), 0, stream,
                       A1, WT1, b_l1, dtf, A2, KTOT, CH,
                       (const void*)nullptr, (const void*)nullptr, (float*)nullptr);
    // layer 2 + fused classifier
    hipLaunchKernelGGL(k_agg, dim3(N_NODES * 16 / 256), dim3(256), 0, stream,
                       row_start, csr_src, A2, A2);
    hipLaunchKernelGGL(k_gemm_mfma, dim3((N_NODES + 127) / 128), dim3(256), 0, stream,
                       A2, WT2, b_l2, dtf, (unsigned short*)nullptr, 0, 0,
                       w_cls, b_cls, (float*)d_out);
}